// Round 7
// baseline (255.069 us; speedup 1.0000x reference)
//
#include <hip/hip_runtime.h>

#define N_E 10000
#define N_KC 2000
#define ALPHA 0.2f

typedef __attribute__((ext_vector_type(8))) short short8;
typedef __attribute__((ext_vector_type(4))) float f32x4;

// ---- static device scratch (fully rewritten every call) ----
__device__ float g_w1a1[256];
__device__ float g_t[2048];
__device__ __align__(16) unsigned short g_W1T_pk[16 * 8 * 512];    // B: W1^T
__device__ __align__(16) unsigned short g_ET_pk[16 * 8 * 512];     // B: E^T
__device__ __align__(16) unsigned short g_rdw_pk[16 * 16 * 512];   // B: rd_w
__device__ __align__(16) unsigned short g_kcWh_pk[16 * 64 * 512];  // B: kcWh^T
// P matrix in MFMA A-fragment layout: [tile][kk][lane][8] bf16, 625 tiles.
__device__ __align__(16) unsigned short g_P_pk[626u * 63 * 512];
__device__ float g_inv[10016];  // 1/softmax-denominator per row

__device__ __forceinline__ unsigned short f2bf(float f) {
  union { float f; unsigned int u; } v; v.f = f;
  unsigned int r = v.u + 0x7FFFu + ((v.u >> 16) & 1u);
  return (unsigned short)(r >> 16);
}

__device__ __forceinline__ void cvt_store4(float4 v, unsigned short* dst) {
  ushort4 o;
  o.x = f2bf(v.x); o.y = f2bf(v.y); o.z = f2bf(v.z); o.w = f2bf(v.w);
  *reinterpret_cast<ushort4*>(dst) = o;
}

// ---- prep: weight packing + w1a1 + zero pads (66 blocks, tiny) ----
__global__ __launch_bounds__(256) void prep_kernel(
    const float* __restrict__ W1, const float* __restrict__ E,
    const float* __restrict__ a, const float* __restrict__ rd_w) {
  int b = blockIdx.x, tid = threadIdx.x;
  if (b < 32) {  // rd_w -> packed B (ct 16 x kt 16)
#pragma unroll
    for (int s2 = 0; s2 < 2; ++s2) {
      int sId = b * 512 + tid + s2 * 256;
      int ct = sId >> 10, rem = sId & 1023;
      int kt = rem >> 6, lane = rem & 63;
      int g = lane >> 4, r = lane & 15;
      const float* src = rd_w + (size_t)(ct * 16 + r) * 512 + kt * 32 + g * 8;
      unsigned short* dst = g_rdw_pk + (size_t)sId * 8;
      cvt_store4(*(const float4*)src, dst);
      cvt_store4(*(const float4*)(src + 4), dst + 4);
    }
  } else if (b < 48) {  // W1^T -> packed B (ct 16 x kt 8)
#pragma unroll
    for (int s2 = 0; s2 < 2; ++s2) {
      int sId = (b - 32) * 512 + tid + s2 * 256;
      int ct = sId >> 9, rem = sId & 511;
      int kt = rem >> 6, lane = rem & 63;
      int g = lane >> 4, r = lane & 15;
      int col = ct * 16 + r, k = kt * 32 + g * 8;
      unsigned short* dst = g_W1T_pk + (size_t)sId * 8;
      ushort4 o0, o1;
      o0.x = f2bf(W1[(k + 0) * 256 + col]); o0.y = f2bf(W1[(k + 1) * 256 + col]);
      o0.z = f2bf(W1[(k + 2) * 256 + col]); o0.w = f2bf(W1[(k + 3) * 256 + col]);
      o1.x = f2bf(W1[(k + 4) * 256 + col]); o1.y = f2bf(W1[(k + 5) * 256 + col]);
      o1.z = f2bf(W1[(k + 6) * 256 + col]); o1.w = f2bf(W1[(k + 7) * 256 + col]);
      *(ushort4*)dst = o0; *(ushort4*)(dst + 4) = o1;
    }
  } else if (b < 64) {  // E^T -> packed B
#pragma unroll
    for (int s2 = 0; s2 < 2; ++s2) {
      int sId = (b - 48) * 512 + tid + s2 * 256;
      int ct = sId >> 9, rem = sId & 511;
      int kt = rem >> 6, lane = rem & 63;
      int g = lane >> 4, r = lane & 15;
      int col = ct * 16 + r, k = kt * 32 + g * 8;
      unsigned short* dst = g_ET_pk + (size_t)sId * 8;
      ushort4 o0, o1;
      o0.x = f2bf(E[(k + 0) * 256 + col]); o0.y = f2bf(E[(k + 1) * 256 + col]);
      o0.z = f2bf(E[(k + 2) * 256 + col]); o0.w = f2bf(E[(k + 3) * 256 + col]);
      o1.x = f2bf(E[(k + 4) * 256 + col]); o1.y = f2bf(E[(k + 5) * 256 + col]);
      o1.z = f2bf(E[(k + 6) * 256 + col]); o1.w = f2bf(E[(k + 7) * 256 + col]);
      *(ushort4*)dst = o0; *(ushort4*)(dst + 4) = o1;
    }
  } else if (b == 64) {  // w1a1
    float acc = 0.f;
    for (int q = 0; q < 64; ++q) {
      float4 wv = *(const float4*)(W1 + (size_t)tid * 256 + q * 4);
      float4 a4 = *(const float4*)(a + q * 4);
      acc += wv.x * a4.x + wv.y * a4.y + wv.z * a4.z + wv.w * a4.w;
    }
    g_w1a1[tid] = acc;
  } else {  // zero pads: kcWh kTiles 62,63 + g_t tail
    for (int idx = tid; idx < 16 * 2 * 512; idx += 256) {
      int ct = idx >> 10, rem = idx & 1023;
      int kt = 62 + (rem >> 9), off = rem & 511;
      g_kcWh_pk[((size_t)ct * 64 + kt) * 512 + off] = 0;
    }
    if (tid < 48) g_t[2000 + tid] = 0.f;
  }
}

// ---- kcWh^T via MFMA (A from f32 kc_h on the fly) + fused t = kcWh@a2 ----
__global__ __launch_bounds__(256) void kc_mfma_kernel(
    const float* __restrict__ kc_h, const float* __restrict__ a) {
  __shared__ float tred[4][4][4];
  int tid = threadIdx.x, lane = tid & 63, w = tid >> 6;
  int r = lane & 15, g = lane >> 4;
  int j0 = blockIdx.x * 16;
  f32x4 acc[4] = {{0.f,0.f,0.f,0.f},{0.f,0.f,0.f,0.f},
                  {0.f,0.f,0.f,0.f},{0.f,0.f,0.f,0.f}};
  for (int kk = 0; kk < 8; ++kk) {
    int k = kk * 32 + g * 8;
    const float* src = kc_h + (size_t)(j0 + r) * 256 + k;
    float4 x0 = *(const float4*)src, x1 = *(const float4*)(src + 4);
    short8 af = {(short)f2bf(x0.x), (short)f2bf(x0.y), (short)f2bf(x0.z),
                 (short)f2bf(x0.w), (short)f2bf(x1.x), (short)f2bf(x1.y),
                 (short)f2bf(x1.z), (short)f2bf(x1.w)};
#pragma unroll
    for (int n = 0; n < 4; ++n) {
      short8 bf = *(const short8*)(g_W1T_pk + ((size_t)(w * 4 + n) * 8 + kk) *
                                                  512 + lane * 8);
      acc[n] = __builtin_amdgcn_mfma_f32_16x16x32_bf16(af, bf, acc[n], 0, 0, 0);
    }
  }
  int j = j0 + g * 4;
  int kt = j >> 5, lsub = ((j >> 3) & 3) * 16 + r, sub = (g & 1) * 4;
#pragma unroll
  for (int n = 0; n < 4; ++n) {
    int ct = w * 4 + n;
    ushort4 o;
    o.x = f2bf(acc[n][0]); o.y = f2bf(acc[n][1]);
    o.z = f2bf(acc[n][2]); o.w = f2bf(acc[n][3]);
    *reinterpret_cast<ushort4*>(
        g_kcWh_pk + ((size_t)ct * 64 + kt) * 512 + lsub * 8 + sub) = o;
  }
  float a2v[4];
#pragma unroll
  for (int n = 0; n < 4; ++n) a2v[n] = a[256 + w * 64 + n * 16 + r];
  float tp[4];
#pragma unroll
  for (int q = 0; q < 4; ++q)
    tp[q] = acc[0][q] * a2v[0] + acc[1][q] * a2v[1] + acc[2][q] * a2v[2] +
            acc[3][q] * a2v[3];
#pragma unroll
  for (int off = 1; off < 16; off <<= 1)
#pragma unroll
    for (int q = 0; q < 4; ++q) tp[q] += __shfl_xor(tp[q], off, 64);
  if (r == 0)
#pragma unroll
    for (int q = 0; q < 4; ++q) tred[w][g][q] = tp[q];
  __syncthreads();
  if (tid < 16)
    g_t[j0 + tid] = tred[0][tid >> 2][tid & 3] + tred[1][tid >> 2][tid & 3] +
                    tred[2][tid >> 2][tid & 3] + tred[3][tid >> 2][tid & 3];
}

// ---- P: streaming gen, COALESCED. One wave per row-quad; lane l reads
// adj[row][i*256+4l..+3] -> 1KB fully contiguous per load instruction.
// Fragment-layout stores are 8B-scattered (L2 merges partial lines).
__global__ __launch_bounds__(256) void p_gen_kernel(
    const float* __restrict__ exh, const int* __restrict__ adj) {
  __shared__ float t_s[2048];
  __shared__ float sv_s[16];
  int tid = threadIdx.x, lane = tid & 63, q = tid >> 6;
  int i0 = blockIdx.x * 16;  // 625*16 == 10000 exactly

  ((float4*)t_s)[tid] = ((const float4*)g_t)[tid];
  ((float4*)t_s)[tid + 256] = ((const float4*)g_t)[tid + 256];

  // sv[row] = exh[row] . w1a1 : 16 threads per row
  {
    int row = tid >> 4, seg = tid & 15;
    const float* xsrc = exh + (size_t)(i0 + row) * 256 + seg * 16;
    const float* wsrc = g_w1a1 + seg * 16;
    float sp = 0.f;
#pragma unroll
    for (int j = 0; j < 4; ++j) {
      float4 x = *(const float4*)(xsrc + j * 4);
      float4 wv = *(const float4*)(wsrc + j * 4);
      sp += x.x * wv.x + x.y * wv.y + x.z * wv.z + x.w * wv.w;
    }
    sp += __shfl_xor(sp, 1, 64);
    sp += __shfl_xor(sp, 2, 64);
    sp += __shfl_xor(sp, 4, 64);
    sp += __shfl_xor(sp, 8, 64);
    if (seg == 0) sv_s[row] = sp;
  }
  __syncthreads();

  unsigned short* tbase = g_P_pk + (size_t)blockIdx.x * 63 * 512;

#pragma unroll 2
  for (int rr = 0; rr < 4; ++rr) {
    int row = q * 4 + rr;  // local row == fragment row index r
    float svr = sv_s[row];
    const int* arow = adj + (size_t)(i0 + row) * N_KC;
    float rsum = 0.f;
#pragma unroll
    for (int i = 0; i < 8; ++i) {
      int c0 = i * 256 + lane * 4;
      int4 av = {0, 0, 0, 0};
      if (c0 + 4 <= N_KC) av = *(const int4*)(arow + c0);  // 1KB coalesced
      float4 tv = *(const float4*)(t_s + c0);              // c0 <= 2044, padded
      float xs[4] = {svr + tv.x, svr + tv.y, svr + tv.z, svr + tv.w};
      int as[4] = {av.x, av.y, av.z, av.w};
      float pv[4];
#pragma unroll
      for (int j = 0; j < 4; ++j) {
        float lx = fmaxf(xs[j], ALPHA * xs[j]);
        pv[j] = (as[j] > 0) ? __expf(lx) : 0.f;
        rsum += pv[j];
      }
      if (c0 < 2016) {  // kk <= 62; cols 2000..2015 store zeros
        unsigned u0 = ((__float_as_uint(pv[0]) + 0x8000u) >> 16) |
                      ((__float_as_uint(pv[1]) + 0x8000u) & 0xFFFF0000u);
        unsigned u1 = ((__float_as_uint(pv[2]) + 0x8000u) >> 16) |
                      ((__float_as_uint(pv[3]) + 0x8000u) & 0xFFFF0000u);
        int kk = c0 >> 5, g2 = (c0 >> 3) & 3, h = (c0 >> 2) & 1;
        uint2 st; st.x = u0; st.y = u1;
        *(uint2*)(tbase + (size_t)kk * 512 + (row + 16 * g2) * 8 + 4 * h) = st;
      }
    }
    // row denominator: full-wave reduce, lane 0 publishes inverse
    rsum += __shfl_xor(rsum, 1, 64);
    rsum += __shfl_xor(rsum, 2, 64);
    rsum += __shfl_xor(rsum, 4, 64);
    rsum += __shfl_xor(rsum, 8, 64);
    rsum += __shfl_xor(rsum, 16, 64);
    rsum += __shfl_xor(rsum, 32, 64);
    if (lane == 0) g_inv[i0 + row] = 1.f / fmaxf(rsum, 1e-30f);
  }
}

// ---- G: 16-row blocks (625 = 2.44 blocks/CU) with whole A-tile in LDS.
// K-loop per wave: 1 ds_read + 2 B-globals + 2 MFMA. Discriminator:
// latency-bound -> ~30-40us; TA-throughput-bound -> stays ~60.
#define FST 536  // feat row stride (shorts)
__global__ __launch_bounds__(512, 4) void g_gemm_kernel(
    const float* __restrict__ exh, const float* __restrict__ rd_b,
    float* __restrict__ out) {
  // A_lds 64512B at 0 | exh_pk 8192B at 65536. feat [16][FST] overlays A.
  __shared__ __align__(16) unsigned char smem[73728];
  __shared__ float inv_s[16];
  unsigned short* A_lds = (unsigned short*)smem;
  unsigned short* exh_pk_s = (unsigned short*)(smem + 65536);
  unsigned short* feat_s = (unsigned short*)smem;

  int tid = threadIdx.x, w = tid >> 6, lane = tid & 63;
  int r = lane & 15, g = lane >> 4;
  int i0 = blockIdx.x * 16;

  // phase 0: stage A tile (63KB), exh fragments, inverse denominators
  {
    const int4* srcA = (const int4*)(g_P_pk + (size_t)blockIdx.x * 63 * 512);
    int4* dstA = (int4*)A_lds;
#pragma unroll
    for (int rnd = 0; rnd < 8; ++rnd) {
      int idx = rnd * 512 + tid;
      if (idx < 4032) dstA[idx] = srcA[idx];
    }
  }
  {
    const float* xsrc = exh + (size_t)(i0 + r) * 256 + w * 32 + g * 8;
    float4 x0 = *(const float4*)xsrc, x1 = *(const float4*)(xsrc + 4);
    unsigned short* dst = exh_pk_s + w * 512 + lane * 8;
    cvt_store4(x0, dst); cvt_store4(x1, dst + 4);
  }
  if (tid < 16) inv_s[tid] = g_inv[i0 + tid];
  __syncthreads();

  // K-loop: wave w owns col-tiles 2w, 2w+1
  f32x4 accP[2] = {{0.f,0.f,0.f,0.f},{0.f,0.f,0.f,0.f}};
  const unsigned short* bb0 =
      g_kcWh_pk + (size_t)(w * 2 + 0) * 64 * 512 + lane * 8;
  const unsigned short* bb1 =
      g_kcWh_pk + (size_t)(w * 2 + 1) * 64 * 512 + lane * 8;
#pragma unroll 7
  for (int kk = 0; kk < 63; ++kk) {
    short8 a  = *(const short8*)(A_lds + (size_t)kk * 512 + lane * 8);
    short8 b0 = *(const short8*)(bb0 + (size_t)kk * 512);
    short8 b1 = *(const short8*)(bb1 + (size_t)kk * 512);
    accP[0] = __builtin_amdgcn_mfma_f32_16x16x32_bf16(a, b0, accP[0], 0, 0, 0);
    accP[1] = __builtin_amdgcn_mfma_f32_16x16x32_bf16(a, b1, accP[1], 0, 0, 0);
  }

  // ---- ex_Eh GEMM ----
  f32x4 accE[2] = {{0.f,0.f,0.f,0.f},{0.f,0.f,0.f,0.f}};
#pragma unroll
  for (int kk = 0; kk < 8; ++kk) {
    short8 a0 = *(const short8*)(exh_pk_s + kk * 512 + lane * 8);
#pragma unroll
    for (int n = 0; n < 2; ++n) {
      short8 bf = *(const short8*)(g_ET_pk + ((size_t)(w * 2 + n) * 8 + kk) *
                                                 512 + lane * 8);
      accE[n] = __builtin_amdgcn_mfma_f32_16x16x32_bf16(a0, bf, accE[n], 0, 0, 0);
    }
  }
  __syncthreads();  // all waves done with A_lds before feat overlay

  // ---- feat = [new_kc | new_kc * ex_Eh] ----
#pragma unroll
  for (int n = 0; n < 2; ++n) {
    int col = w * 32 + n * 16 + r;
#pragma unroll
    for (int q2 = 0; q2 < 4; ++q2) {
      int row = g * 4 + q2;
      float nk = accP[n][q2] * inv_s[row];
      feat_s[(size_t)row * FST + col] = f2bf(nk);
      feat_s[(size_t)row * FST + 256 + col] = f2bf(nk * accE[n][q2]);
    }
  }
  __syncthreads();

  // ---- epilogue GEMM: feat(16x512) @ rd_w^T + bias, ELU ----
  f32x4 accO[2] = {{0.f,0.f,0.f,0.f},{0.f,0.f,0.f,0.f}};
#pragma unroll
  for (int kt = 0; kt < 16; ++kt) {
    int k = kt * 32 + g * 8;
    short8 a0 = *(const short8*)(feat_s + (size_t)r * FST + k);
#pragma unroll
    for (int n = 0; n < 2; ++n) {
      short8 bf = *(const short8*)(g_rdw_pk + ((size_t)(w * 2 + n) * 16 + kt) *
                                                  512 + lane * 8);
      accO[n] = __builtin_amdgcn_mfma_f32_16x16x32_bf16(a0, bf, accO[n], 0, 0, 0);
    }
  }
#pragma unroll
  for (int n = 0; n < 2; ++n) {
    int col = w * 32 + n * 16 + r;
    float bias = rd_b[col];
#pragma unroll
    for (int q2 = 0; q2 < 4; ++q2) {
      int row = i0 + g * 4 + q2;
      float x = accO[n][q2] + bias;
      float res = x > 0.f ? x : (__expf(x) - 1.f);
      out[(size_t)row * 256 + col] = res;
    }
  }
}

extern "C" void kernel_launch(void* const* d_in, const int* in_sizes, int n_in,
                              void* d_out, int out_size, void* d_ws,
                              size_t ws_size, hipStream_t stream) {
  const float* exh  = (const float*)d_in[0];
  const float* kc_h = (const float*)d_in[1];
  const int*   adj  = (const int*)d_in[2];
  const float* W1   = (const float*)d_in[3];
  const float* E    = (const float*)d_in[4];
  const float* a    = (const float*)d_in[5];
  const float* rd_w = (const float*)d_in[6];
  const float* rd_b = (const float*)d_in[7];
  float* out = (float*)d_out;

  prep_kernel<<<66, 256, 0, stream>>>(W1, E, a, rd_w);
  kc_mfma_kernel<<<N_KC / 16, 256, 0, stream>>>(kc_h, a);
  p_gen_kernel<<<N_E / 16, 256, 0, stream>>>(exh, adj);
  g_gemm_kernel<<<N_E / 16, 512, 0, stream>>>(exh, rd_b, out);
}

// Round 8
// 218.436 us; speedup vs baseline: 1.1677x; 1.1677x over previous
//
#include <hip/hip_runtime.h>

#define N_E 10000
#define N_KC 2000
#define ALPHA 0.2f

typedef __attribute__((ext_vector_type(8))) short short8;
typedef __attribute__((ext_vector_type(4))) float f32x4;

// ---- static device scratch (fully rewritten every call) ----
__device__ float g_w1a1[256];
__device__ float g_t[2048];
__device__ __align__(16) unsigned short g_W1T_pk[16 * 8 * 512];    // B: W1^T
__device__ __align__(16) unsigned short g_ET_pk[16 * 8 * 512];     // B: E^T
__device__ __align__(16) unsigned short g_rdw_pk[16 * 16 * 512];   // B: rd_w
__device__ __align__(16) unsigned short g_kcWh_pk[16 * 64 * 512];  // B: kcWh^T

__device__ __forceinline__ unsigned short f2bf(float f) {
  union { float f; unsigned int u; } v; v.f = f;
  unsigned int r = v.u + 0x7FFFu + ((v.u >> 16) & 1u);
  return (unsigned short)(r >> 16);
}

__device__ __forceinline__ void cvt_store4(float4 v, unsigned short* dst) {
  ushort4 o;
  o.x = f2bf(v.x); o.y = f2bf(v.y); o.z = f2bf(v.z); o.w = f2bf(v.w);
  *reinterpret_cast<ushort4*>(dst) = o;
}

// ---- prep: weight packing + w1a1 + zero pads (66 blocks, tiny) ----
__global__ __launch_bounds__(256) void prep_kernel(
    const float* __restrict__ W1, const float* __restrict__ E,
    const float* __restrict__ a, const float* __restrict__ rd_w) {
  int b = blockIdx.x, tid = threadIdx.x;
  if (b < 32) {  // rd_w -> packed B (ct 16 x kt 16)
#pragma unroll
    for (int s2 = 0; s2 < 2; ++s2) {
      int sId = b * 512 + tid + s2 * 256;
      int ct = sId >> 10, rem = sId & 1023;
      int kt = rem >> 6, lane = rem & 63;
      int g = lane >> 4, r = lane & 15;
      const float* src = rd_w + (size_t)(ct * 16 + r) * 512 + kt * 32 + g * 8;
      unsigned short* dst = g_rdw_pk + (size_t)sId * 8;
      cvt_store4(*(const float4*)src, dst);
      cvt_store4(*(const float4*)(src + 4), dst + 4);
    }
  } else if (b < 48) {  // W1^T -> packed B (ct 16 x kt 8)
#pragma unroll
    for (int s2 = 0; s2 < 2; ++s2) {
      int sId = (b - 32) * 512 + tid + s2 * 256;
      int ct = sId >> 9, rem = sId & 511;
      int kt = rem >> 6, lane = rem & 63;
      int g = lane >> 4, r = lane & 15;
      int col = ct * 16 + r, k = kt * 32 + g * 8;
      unsigned short* dst = g_W1T_pk + (size_t)sId * 8;
      ushort4 o0, o1;
      o0.x = f2bf(W1[(k + 0) * 256 + col]); o0.y = f2bf(W1[(k + 1) * 256 + col]);
      o0.z = f2bf(W1[(k + 2) * 256 + col]); o0.w = f2bf(W1[(k + 3) * 256 + col]);
      o1.x = f2bf(W1[(k + 4) * 256 + col]); o1.y = f2bf(W1[(k + 5) * 256 + col]);
      o1.z = f2bf(W1[(k + 6) * 256 + col]); o1.w = f2bf(W1[(k + 7) * 256 + col]);
      *(ushort4*)dst = o0; *(ushort4*)(dst + 4) = o1;
    }
  } else if (b < 64) {  // E^T -> packed B
#pragma unroll
    for (int s2 = 0; s2 < 2; ++s2) {
      int sId = (b - 48) * 512 + tid + s2 * 256;
      int ct = sId >> 9, rem = sId & 511;
      int kt = rem >> 6, lane = rem & 63;
      int g = lane >> 4, r = lane & 15;
      int col = ct * 16 + r, k = kt * 32 + g * 8;
      unsigned short* dst = g_ET_pk + (size_t)sId * 8;
      ushort4 o0, o1;
      o0.x = f2bf(E[(k + 0) * 256 + col]); o0.y = f2bf(E[(k + 1) * 256 + col]);
      o0.z = f2bf(E[(k + 2) * 256 + col]); o0.w = f2bf(E[(k + 3) * 256 + col]);
      o1.x = f2bf(E[(k + 4) * 256 + col]); o1.y = f2bf(E[(k + 5) * 256 + col]);
      o1.z = f2bf(E[(k + 6) * 256 + col]); o1.w = f2bf(E[(k + 7) * 256 + col]);
      *(ushort4*)dst = o0; *(ushort4*)(dst + 4) = o1;
    }
  } else if (b == 64) {  // w1a1
    float acc = 0.f;
    for (int q = 0; q < 64; ++q) {
      float4 wv = *(const float4*)(W1 + (size_t)tid * 256 + q * 4);
      float4 a4 = *(const float4*)(a + q * 4);
      acc += wv.x * a4.x + wv.y * a4.y + wv.z * a4.z + wv.w * a4.w;
    }
    g_w1a1[tid] = acc;
  } else {  // zero pads: kcWh kTiles 62,63 + g_t tail
    for (int idx = tid; idx < 16 * 2 * 512; idx += 256) {
      int ct = idx >> 10, rem = idx & 1023;
      int kt = 62 + (rem >> 9), off = rem & 511;
      g_kcWh_pk[((size_t)ct * 64 + kt) * 512 + off] = 0;
    }
    if (tid < 48) g_t[2000 + tid] = 0.f;
  }
}

// ---- kcWh^T via MFMA (A from f32 kc_h on the fly) + fused t = kcWh@a2 ----
__global__ __launch_bounds__(256) void kc_mfma_kernel(
    const float* __restrict__ kc_h, const float* __restrict__ a) {
  __shared__ float tred[4][4][4];
  int tid = threadIdx.x, lane = tid & 63, w = tid >> 6;
  int r = lane & 15, g = lane >> 4;
  int j0 = blockIdx.x * 16;
  f32x4 acc[4] = {{0.f,0.f,0.f,0.f},{0.f,0.f,0.f,0.f},
                  {0.f,0.f,0.f,0.f},{0.f,0.f,0.f,0.f}};
  for (int kk = 0; kk < 8; ++kk) {
    int k = kk * 32 + g * 8;
    const float* src = kc_h + (size_t)(j0 + r) * 256 + k;
    float4 x0 = *(const float4*)src, x1 = *(const float4*)(src + 4);
    short8 af = {(short)f2bf(x0.x), (short)f2bf(x0.y), (short)f2bf(x0.z),
                 (short)f2bf(x0.w), (short)f2bf(x1.x), (short)f2bf(x1.y),
                 (short)f2bf(x1.z), (short)f2bf(x1.w)};
#pragma unroll
    for (int n = 0; n < 4; ++n) {
      short8 bf = *(const short8*)(g_W1T_pk + ((size_t)(w * 4 + n) * 8 + kk) *
                                                  512 + lane * 8);
      acc[n] = __builtin_amdgcn_mfma_f32_16x16x32_bf16(af, bf, acc[n], 0, 0, 0);
    }
  }
  int j = j0 + g * 4;
  int kt = j >> 5, lsub = ((j >> 3) & 3) * 16 + r, sub = (g & 1) * 4;
#pragma unroll
  for (int n = 0; n < 4; ++n) {
    int ct = w * 4 + n;
    ushort4 o;
    o.x = f2bf(acc[n][0]); o.y = f2bf(acc[n][1]);
    o.z = f2bf(acc[n][2]); o.w = f2bf(acc[n][3]);
    *reinterpret_cast<ushort4*>(
        g_kcWh_pk + ((size_t)ct * 64 + kt) * 512 + lsub * 8 + sub) = o;
  }
  float a2v[4];
#pragma unroll
  for (int n = 0; n < 4; ++n) a2v[n] = a[256 + w * 64 + n * 16 + r];
  float tp[4];
#pragma unroll
  for (int q = 0; q < 4; ++q)
    tp[q] = acc[0][q] * a2v[0] + acc[1][q] * a2v[1] + acc[2][q] * a2v[2] +
            acc[3][q] * a2v[3];
#pragma unroll
  for (int off = 1; off < 16; off <<= 1)
#pragma unroll
    for (int q = 0; q < 4; ++q) tp[q] += __shfl_xor(tp[q], off, 64);
  if (r == 0)
#pragma unroll
    for (int q = 0; q < 4; ++q) tred[w][g][q] = tp[q];
  __syncthreads();
  if (tid < 16)
    g_t[j0 + tid] = tred[0][tid >> 2][tid & 3] + tred[1][tid >> 2][tid & 3] +
                    tred[2][tid >> 2][tid & 3] + tred[3][tid >> 2][tid & 3];
}

// ---- main (fused, 625 blocks x 16 rows): gen P into LDS (swizzled frag
// layout, 16B stores), then R7-style barrier-free K-loop (A: ds_read,
// B: 2 globals, 4 MFMA chains via kk&1 split), accE direct-from-global,
// feat overlay, epilogue GEMM. No P round-trip through HBM.
#define FST 536  // feat row stride (shorts)
__global__ __launch_bounds__(512, 2) void main_kernel(
    const float* __restrict__ exh, const int* __restrict__ adj,
    const float* __restrict__ rd_b, float* __restrict__ out) {
  // P_lds [63][512]u16 swizzled (64512B) | t_s [2048]f32 (8192B).
  // feat [16][FST]u16 (17152B) overlays P_lds after the K-loop.
  __shared__ __align__(16) unsigned char smem[64512 + 8192];
  __shared__ float sv_s[16];
  __shared__ float inv_s[16];
  unsigned short* P_lds = (unsigned short*)smem;
  float* t_s = (float*)(smem + 64512);
  unsigned short* feat_s = (unsigned short*)smem;

  int tid = threadIdx.x, w = tid >> 6, lane = tid & 63;
  int i0 = blockIdx.x * 16;  // 625*16 == 10000: no row guards anywhere

  // ---- phase 0: t_s stage + sv[row] = exh[row] . w1a1 ----
  ((float4*)t_s)[tid] = ((const float4*)g_t)[tid];
  {
    int row = tid >> 5, seg = tid & 31;  // 32 threads per row, 8 elems each
    const float* xsrc = exh + (size_t)(i0 + row) * 256 + seg * 8;
    float4 x0 = *(const float4*)xsrc, x1 = *(const float4*)(xsrc + 4);
    const float* wsrc = g_w1a1 + seg * 8;
    float4 w0 = *(const float4*)wsrc, w1 = *(const float4*)(wsrc + 4);
    float sp = x0.x * w0.x + x0.y * w0.y + x0.z * w0.z + x0.w * w0.w +
               x1.x * w1.x + x1.y * w1.y + x1.z * w1.z + x1.w * w1.w;
    sp += __shfl_xor(sp, 1, 64);
    sp += __shfl_xor(sp, 2, 64);
    sp += __shfl_xor(sp, 4, 64);
    sp += __shfl_xor(sp, 8, 64);
    sp += __shfl_xor(sp, 16, 64);
    if ((tid & 31) == 0) sv_s[row] = sp;
  }
  __syncthreads();

  // ---- gen phase: wave w owns rows 2w, 2w+1. Lane (kks=lane>>2, g=lane&3)
  // computes cols kk*32+g*8..+7 for kk = v*16+kks. adj reads: per wave-instr
  // the 64 lanes cover 2KB contiguous. Store: one 16B frag-slot per task,
  // bank-swizzled: slot = (row ^ (kk&15)) | (g<<4)  [kk&15 == kks].
  {
    int kks = lane >> 2, g = lane & 3;
    float dsum[2] = {0.f, 0.f};
#pragma unroll
    for (int rr = 0; rr < 2; ++rr) {
      int row = w * 2 + rr;
      float svr = sv_s[row];
      const int* arow = adj + (size_t)(i0 + row) * N_KC;
#pragma unroll
      for (int v = 0; v < 4; ++v) {
        int kk = v * 16 + kks;          // 0..63 (kk==63 lanes: compute-only)
        int c0 = kk * 32 + g * 8;       // <= 2040
        int4 a0v = {0, 0, 0, 0}, a1v = {0, 0, 0, 0};
        if (c0 + 4 <= N_KC) a0v = *(const int4*)(arow + c0);
        if (c0 + 8 <= N_KC) a1v = *(const int4*)(arow + c0 + 4);
        float4 t0 = *(const float4*)(t_s + c0);   // t_s zero-padded to 2048
        float4 t1 = *(const float4*)(t_s + c0 + 4);
        float tv[8] = {t0.x, t0.y, t0.z, t0.w, t1.x, t1.y, t1.z, t1.w};
        int av[8] = {a0v.x, a0v.y, a0v.z, a0v.w, a1v.x, a1v.y, a1v.z, a1v.w};
        unsigned ub[8];
#pragma unroll
        for (int j = 0; j < 8; ++j) {
          float x = svr + tv[j];
          float lx = fmaxf(x, ALPHA * x);
          float pv = (av[j] > 0) ? __expf(lx) : 0.f;
          dsum[rr] += pv;
          ub[j] = __float_as_uint(pv) + 0x8000u;
        }
        int4 pk;
        pk.x = (int)((ub[0] >> 16) | (ub[1] & 0xFFFF0000u));
        pk.y = (int)((ub[2] >> 16) | (ub[3] & 0xFFFF0000u));
        pk.z = (int)((ub[4] >> 16) | (ub[5] & 0xFFFF0000u));
        pk.w = (int)((ub[6] >> 16) | (ub[7] & 0xFFFF0000u));
        if (kk < 63) {
          int slot = (row ^ kks) | (g << 4);
          *(int4*)(P_lds + ((size_t)kk << 9) + (slot << 3)) = pk;
        }
      }
    }
#pragma unroll
    for (int rr = 0; rr < 2; ++rr) {
      float d = dsum[rr];
      d += __shfl_xor(d, 1, 64);
      d += __shfl_xor(d, 2, 64);
      d += __shfl_xor(d, 4, 64);
      d += __shfl_xor(d, 8, 64);
      d += __shfl_xor(d, 16, 64);
      d += __shfl_xor(d, 32, 64);
      if (lane == 0) inv_s[w * 2 + rr] = 1.f / fmaxf(d, 1e-30f);
    }
  }
  __syncthreads();

  // ---- K-loop: wave w owns col-tiles 2w, 2w+1. A from swizzled P_lds,
  // B from L2-resident g_kcWh_pk. 4 MFMA chains (2 ct x kk-parity split).
  f32x4 accP[2][2] = {{{0.f,0.f,0.f,0.f},{0.f,0.f,0.f,0.f}},
                      {{0.f,0.f,0.f,0.f},{0.f,0.f,0.f,0.f}}};
  const unsigned short* bb0 =
      g_kcWh_pk + (size_t)(w * 2 + 0) * 64 * 512 + lane * 8;
  const unsigned short* bb1 =
      g_kcWh_pk + (size_t)(w * 2 + 1) * 64 * 512 + lane * 8;
#pragma unroll 7
  for (int kk = 0; kk < 63; ++kk) {
    short8 a = *(const short8*)(P_lds + ((size_t)kk << 9) +
                                ((lane ^ (kk & 15)) << 3));
    short8 b0 = *(const short8*)(bb0 + ((size_t)kk << 9));
    short8 b1 = *(const short8*)(bb1 + ((size_t)kk << 9));
    accP[0][kk & 1] = __builtin_amdgcn_mfma_f32_16x16x32_bf16(a, b0, accP[0][kk & 1], 0, 0, 0);
    accP[1][kk & 1] = __builtin_amdgcn_mfma_f32_16x16x32_bf16(a, b1, accP[1][kk & 1], 0, 0, 0);
  }

  // ---- ex_Eh GEMM: A-frags built directly from global exh (L2/L3-hot) ----
  int r2 = lane & 15, g2 = lane >> 4;
  f32x4 accE[2] = {{0.f,0.f,0.f,0.f},{0.f,0.f,0.f,0.f}};
#pragma unroll
  for (int kk8 = 0; kk8 < 8; ++kk8) {
    const float* xs = exh + (size_t)(i0 + r2) * 256 + kk8 * 32 + g2 * 8;
    float4 x0 = *(const float4*)xs, x1 = *(const float4*)(xs + 4);
    short8 a0 = {(short)f2bf(x0.x), (short)f2bf(x0.y), (short)f2bf(x0.z),
                 (short)f2bf(x0.w), (short)f2bf(x1.x), (short)f2bf(x1.y),
                 (short)f2bf(x1.z), (short)f2bf(x1.w)};
#pragma unroll
    for (int n = 0; n < 2; ++n) {
      short8 bf = *(const short8*)(g_ET_pk + ((size_t)(w * 2 + n) * 8 + kk8) *
                                                 512 + lane * 8);
      accE[n] = __builtin_amdgcn_mfma_f32_16x16x32_bf16(a0, bf, accE[n], 0, 0, 0);
    }
  }
  __syncthreads();  // all waves done reading P_lds before feat overlay

  // ---- feat = [new_kc | new_kc * ex_Eh] (overlays P_lds) ----
#pragma unroll
  for (int n = 0; n < 2; ++n) {
    int col = w * 32 + n * 16 + r2;
#pragma unroll
    for (int q = 0; q < 4; ++q) {
      int row = g2 * 4 + q;
      float nk = (accP[n][0][q] + accP[n][1][q]) * inv_s[row];
      feat_s[(size_t)row * FST + col] = f2bf(nk);
      feat_s[(size_t)row * FST + 256 + col] = f2bf(nk * accE[n][q]);
    }
  }
  __syncthreads();

  // ---- epilogue GEMM: feat(16x512) @ rd_w^T + bias, ELU ----
  f32x4 accO[2] = {{0.f,0.f,0.f,0.f},{0.f,0.f,0.f,0.f}};
#pragma unroll
  for (int kt = 0; kt < 16; ++kt) {
    int k = kt * 32 + g2 * 8;
    short8 a0 = *(const short8*)(feat_s + (size_t)r2 * FST + k);
#pragma unroll
    for (int n = 0; n < 2; ++n) {
      short8 bf = *(const short8*)(g_rdw_pk + ((size_t)(w * 2 + n) * 16 + kt) *
                                                  512 + lane * 8);
      accO[n] = __builtin_amdgcn_mfma_f32_16x16x32_bf16(a0, bf, accO[n], 0, 0, 0);
    }
  }
#pragma unroll
  for (int n = 0; n < 2; ++n) {
    int col = w * 32 + n * 16 + r2;
    float bias = rd_b[col];
#pragma unroll
    for (int q = 0; q < 4; ++q) {
      int row = i0 + g2 * 4 + q;
      float x = accO[n][q] + bias;
      float res = x > 0.f ? x : (__expf(x) - 1.f);
      out[(size_t)row * 256 + col] = res;
    }
  }
}

extern "C" void kernel_launch(void* const* d_in, const int* in_sizes, int n_in,
                              void* d_out, int out_size, void* d_ws,
                              size_t ws_size, hipStream_t stream) {
  const float* exh  = (const float*)d_in[0];
  const float* kc_h = (const float*)d_in[1];
  const int*   adj  = (const int*)d_in[2];
  const float* W1   = (const float*)d_in[3];
  const float* E    = (const float*)d_in[4];
  const float* a    = (const float*)d_in[5];
  const float* rd_w = (const float*)d_in[6];
  const float* rd_b = (const float*)d_in[7];
  float* out = (float*)d_out;

  prep_kernel<<<66, 256, 0, stream>>>(W1, E, a, rd_w);
  kc_mfma_kernel<<<N_KC / 16, 256, 0, stream>>>(kc_h, a);
  main_kernel<<<N_E / 16, 512, 0, stream>>>(exh, adj, rd_b, out);
}

// Round 9
// 194.297 us; speedup vs baseline: 1.3128x; 1.1242x over previous
//
#include <hip/hip_runtime.h>

#define N_E 10000
#define N_KC 2000
#define ALPHA 0.2f

typedef __attribute__((ext_vector_type(8))) short short8;
typedef __attribute__((ext_vector_type(4))) float f32x4;

// ---- static device scratch (fully rewritten every call) ----
__device__ float g_w1a1[256];
__device__ float g_t[2048];
__device__ __align__(16) unsigned short g_W1T_pk[16 * 8 * 512];    // B: W1^T
__device__ __align__(16) unsigned short g_ET_pk[16 * 8 * 512];     // B: E^T
__device__ __align__(16) unsigned short g_rdw_pk[16 * 16 * 512];   // B: rd_w
__device__ __align__(16) unsigned short g_kcWh_pk[16 * 64 * 512];  // B: kcWh^T

__device__ __forceinline__ unsigned short f2bf(float f) {
  union { float f; unsigned int u; } v; v.f = f;
  unsigned int r = v.u + 0x7FFFu + ((v.u >> 16) & 1u);
  return (unsigned short)(r >> 16);
}

__device__ __forceinline__ void cvt_store4(float4 v, unsigned short* dst) {
  ushort4 o;
  o.x = f2bf(v.x); o.y = f2bf(v.y); o.z = f2bf(v.z); o.w = f2bf(v.w);
  *reinterpret_cast<ushort4*>(dst) = o;
}

// ---- prep: weight packing + w1a1 + zero pads (66 blocks, tiny) ----
__global__ __launch_bounds__(256) void prep_kernel(
    const float* __restrict__ W1, const float* __restrict__ E,
    const float* __restrict__ a, const float* __restrict__ rd_w) {
  int b = blockIdx.x, tid = threadIdx.x;
  if (b < 32) {  // rd_w -> packed B (ct 16 x kt 16)
#pragma unroll
    for (int s2 = 0; s2 < 2; ++s2) {
      int sId = b * 512 + tid + s2 * 256;
      int ct = sId >> 10, rem = sId & 1023;
      int kt = rem >> 6, lane = rem & 63;
      int g = lane >> 4, r = lane & 15;
      const float* src = rd_w + (size_t)(ct * 16 + r) * 512 + kt * 32 + g * 8;
      unsigned short* dst = g_rdw_pk + (size_t)sId * 8;
      cvt_store4(*(const float4*)src, dst);
      cvt_store4(*(const float4*)(src + 4), dst + 4);
    }
  } else if (b < 48) {  // W1^T -> packed B (ct 16 x kt 8)
#pragma unroll
    for (int s2 = 0; s2 < 2; ++s2) {
      int sId = (b - 32) * 512 + tid + s2 * 256;
      int ct = sId >> 9, rem = sId & 511;
      int kt = rem >> 6, lane = rem & 63;
      int g = lane >> 4, r = lane & 15;
      int col = ct * 16 + r, k = kt * 32 + g * 8;
      unsigned short* dst = g_W1T_pk + (size_t)sId * 8;
      ushort4 o0, o1;
      o0.x = f2bf(W1[(k + 0) * 256 + col]); o0.y = f2bf(W1[(k + 1) * 256 + col]);
      o0.z = f2bf(W1[(k + 2) * 256 + col]); o0.w = f2bf(W1[(k + 3) * 256 + col]);
      o1.x = f2bf(W1[(k + 4) * 256 + col]); o1.y = f2bf(W1[(k + 5) * 256 + col]);
      o1.z = f2bf(W1[(k + 6) * 256 + col]); o1.w = f2bf(W1[(k + 7) * 256 + col]);
      *(ushort4*)dst = o0; *(ushort4*)(dst + 4) = o1;
    }
  } else if (b < 64) {  // E^T -> packed B
#pragma unroll
    for (int s2 = 0; s2 < 2; ++s2) {
      int sId = (b - 48) * 512 + tid + s2 * 256;
      int ct = sId >> 9, rem = sId & 511;
      int kt = rem >> 6, lane = rem & 63;
      int g = lane >> 4, r = lane & 15;
      int col = ct * 16 + r, k = kt * 32 + g * 8;
      unsigned short* dst = g_ET_pk + (size_t)sId * 8;
      ushort4 o0, o1;
      o0.x = f2bf(E[(k + 0) * 256 + col]); o0.y = f2bf(E[(k + 1) * 256 + col]);
      o0.z = f2bf(E[(k + 2) * 256 + col]); o0.w = f2bf(E[(k + 3) * 256 + col]);
      o1.x = f2bf(E[(k + 4) * 256 + col]); o1.y = f2bf(E[(k + 5) * 256 + col]);
      o1.z = f2bf(E[(k + 6) * 256 + col]); o1.w = f2bf(E[(k + 7) * 256 + col]);
      *(ushort4*)dst = o0; *(ushort4*)(dst + 4) = o1;
    }
  } else if (b == 64) {  // w1a1
    float acc = 0.f;
    for (int q = 0; q < 64; ++q) {
      float4 wv = *(const float4*)(W1 + (size_t)tid * 256 + q * 4);
      float4 a4 = *(const float4*)(a + q * 4);
      acc += wv.x * a4.x + wv.y * a4.y + wv.z * a4.z + wv.w * a4.w;
    }
    g_w1a1[tid] = acc;
  } else {  // zero pads: kcWh kTiles 62,63 + g_t tail
    for (int idx = tid; idx < 16 * 2 * 512; idx += 256) {
      int ct = idx >> 10, rem = idx & 1023;
      int kt = 62 + (rem >> 9), off = rem & 511;
      g_kcWh_pk[((size_t)ct * 64 + kt) * 512 + off] = 0;
    }
    if (tid < 48) g_t[2000 + tid] = 0.f;
  }
}

// ---- kcWh^T via MFMA (A from f32 kc_h on the fly) + fused t = kcWh@a2 ----
__global__ __launch_bounds__(256) void kc_mfma_kernel(
    const float* __restrict__ kc_h, const float* __restrict__ a) {
  __shared__ float tred[4][4][4];
  int tid = threadIdx.x, lane = tid & 63, w = tid >> 6;
  int r = lane & 15, g = lane >> 4;
  int j0 = blockIdx.x * 16;
  f32x4 acc[4] = {{0.f,0.f,0.f,0.f},{0.f,0.f,0.f,0.f},
                  {0.f,0.f,0.f,0.f},{0.f,0.f,0.f,0.f}};
  for (int kk = 0; kk < 8; ++kk) {
    int k = kk * 32 + g * 8;
    const float* src = kc_h + (size_t)(j0 + r) * 256 + k;
    float4 x0 = *(const float4*)src, x1 = *(const float4*)(src + 4);
    short8 af = {(short)f2bf(x0.x), (short)f2bf(x0.y), (short)f2bf(x0.z),
                 (short)f2bf(x0.w), (short)f2bf(x1.x), (short)f2bf(x1.y),
                 (short)f2bf(x1.z), (short)f2bf(x1.w)};
#pragma unroll
    for (int n = 0; n < 4; ++n) {
      short8 bf = *(const short8*)(g_W1T_pk + ((size_t)(w * 4 + n) * 8 + kk) *
                                                  512 + lane * 8);
      acc[n] = __builtin_amdgcn_mfma_f32_16x16x32_bf16(af, bf, acc[n], 0, 0, 0);
    }
  }
  int j = j0 + g * 4;
  int kt = j >> 5, lsub = ((j >> 3) & 3) * 16 + r, sub = (g & 1) * 4;
#pragma unroll
  for (int n = 0; n < 4; ++n) {
    int ct = w * 4 + n;
    ushort4 o;
    o.x = f2bf(acc[n][0]); o.y = f2bf(acc[n][1]);
    o.z = f2bf(acc[n][2]); o.w = f2bf(acc[n][3]);
    *reinterpret_cast<ushort4*>(
        g_kcWh_pk + ((size_t)ct * 64 + kt) * 512 + lsub * 8 + sub) = o;
  }
  float a2v[4];
#pragma unroll
  for (int n = 0; n < 4; ++n) a2v[n] = a[256 + w * 64 + n * 16 + r];
  float tp[4];
#pragma unroll
  for (int q = 0; q < 4; ++q)
    tp[q] = acc[0][q] * a2v[0] + acc[1][q] * a2v[1] + acc[2][q] * a2v[2] +
            acc[3][q] * a2v[3];
#pragma unroll
  for (int off = 1; off < 16; off <<= 1)
#pragma unroll
    for (int q = 0; q < 4; ++q) tp[q] += __shfl_xor(tp[q], off, 64);
  if (r == 0)
#pragma unroll
    for (int q = 0; q < 4; ++q) tred[w][g][q] = tp[q];
  __syncthreads();
  if (tid < 16)
    g_t[j0 + tid] = tred[0][tid >> 2][tid & 3] + tred[1][tid >> 2][tid & 3] +
                    tred[2][tid >> 2][tid & 3] + tred[3][tid >> 2][tid & 3];
}

// ---- main: 625 blocks x 1024 threads (16 waves). Wave w owns ONE 16x16
// output col-tile (ct = w) in all three GEMMs -> minimal VGPRs, and
// __launch_bounds__(1024,8) + 79.1KB LDS -> 2 blocks/CU = 32 waves/CU
// (full occupancy), the one lever measured to speed the latency-bound
// K-loop (R6 ~10 w/CU: 60us -> R7 ~16 w/CU: ~50us). gen keeps R0's
// conflict-free mapping (t_s broadcast; kk uniform per wave).
#define FST 536  // feat row stride (shorts)
__global__ __launch_bounds__(1024, 8) void main_kernel(
    const float* __restrict__ exh, const int* __restrict__ adj,
    const float* __restrict__ rd_b, float* __restrict__ out) {
  // blob (80960 B total; +runtime pad stays under 80 KB/block):
  //   [0, 64512)       P_lds [63][512]u16 frag layout; feat overlays later
  //   [64512, 64576)   denom_s 16 f32
  //   [64576, 64640)   inv_s   16 f32
  //   [64640, 64704)   sv_s    16 f32
  //   [64704, 72768)   t_s     2016 f32
  //   [72768, 80960)   exh_pk  [8][512]u16
  __shared__ __align__(16) unsigned char smem[80960];
  unsigned short* P_lds = (unsigned short*)smem;
  unsigned short* feat_s = (unsigned short*)smem;
  float* denom_s = (float*)(smem + 64512);
  float* inv_s = (float*)(smem + 64576);
  float* sv_s = (float*)(smem + 64640);
  float* t_s = (float*)(smem + 64704);
  unsigned short* exh_pk_s = (unsigned short*)(smem + 72768);

  int tid = threadIdx.x, w = tid >> 6, lane = tid & 63;
  int r = lane & 15, g = lane >> 4;
  int i0 = blockIdx.x * 16;  // 625*16 == 10000: no row guards

  // ---- phase 0: t_s (2016 f32), denom init, sv + exh fragment staging ----
  if (tid < 1008) ((float2*)t_s)[tid] = ((const float2*)g_t)[tid];
  if (tid < 16) denom_s[tid] = 0.f;
  {
    // wave w handles row w: full-row coalesced read (1KB/wave-instr)
    const float* xsrc = exh + (size_t)(i0 + w) * 256 + lane * 4;
    float4 x = *(const float4*)xsrc;
    const float* wsrc = g_w1a1 + lane * 4;
    float4 wv = *(const float4*)wsrc;
    float sp = x.x * wv.x + x.y * wv.y + x.z * wv.z + x.w * wv.w;
#pragma unroll
    for (int off = 1; off < 64; off <<= 1) sp += __shfl_xor(sp, off, 64);
    if (lane == 0) sv_s[w] = sp;
    // pack exh[row w][4*lane..+4] into MFMA A-fragment layout
    ushort4 o;
    o.x = f2bf(x.x); o.y = f2bf(x.y); o.z = f2bf(x.z); o.w = f2bf(x.w);
    int c = lane * 4;
    int kk8 = c >> 5, gf = (c >> 3) & 3, hh = (c >> 2) & 1;
    *(ushort4*)(exh_pk_s + kk8 * 512 + (w + 16 * gf) * 8 + hh * 4) = o;
  }
  __syncthreads();

  // ---- gen: wave w owns kk = w*4+v (v=0..3); thread (r,g) computes
  // P[r][kk*32+g*8..+8]. t_s read is a 16-lane broadcast (conflict-free);
  // adj read = 128B contiguous per row. Store = linear frag slot (2-way).
  {
    float svr = sv_s[r];
    const int* arow = adj + (size_t)(i0 + r) * N_KC;
    float dsum = 0.f;
#pragma unroll 2
    for (int v = 0; v < 4; ++v) {
      int kk = w * 4 + v;
      if (kk < 63) {
        int c0 = kk * 32 + g * 8;
        int4 a0v = {0, 0, 0, 0}, a1v = {0, 0, 0, 0};
        if (c0 + 4 <= N_KC) a0v = *(const int4*)(arow + c0);
        if (c0 + 8 <= N_KC) a1v = *(const int4*)(arow + c0 + 4);
        float4 t0 = *(const float4*)(t_s + c0);      // max idx 2015 ✓
        float4 t1 = *(const float4*)(t_s + c0 + 4);
        float tv[8] = {t0.x, t0.y, t0.z, t0.w, t1.x, t1.y, t1.z, t1.w};
        int av[8] = {a0v.x, a0v.y, a0v.z, a0v.w, a1v.x, a1v.y, a1v.z, a1v.w};
        unsigned ub[8];
#pragma unroll
        for (int j = 0; j < 8; ++j) {
          float x = svr + tv[j];
          float lx = fmaxf(x, ALPHA * x);
          float pv = (av[j] > 0) ? __expf(lx) : 0.f;
          dsum += pv;
          ub[j] = __float_as_uint(pv) + 0x8000u;
        }
        int4 pk;
        pk.x = (int)((ub[0] >> 16) | (ub[1] & 0xFFFF0000u));
        pk.y = (int)((ub[2] >> 16) | (ub[3] & 0xFFFF0000u));
        pk.z = (int)((ub[4] >> 16) | (ub[5] & 0xFFFF0000u));
        pk.w = (int)((ub[6] >> 16) | (ub[7] & 0xFFFF0000u));
        *(int4*)(P_lds + (size_t)kk * 512 + lane * 8) = pk;
      }
    }
    dsum += __shfl_xor(dsum, 16, 64);
    dsum += __shfl_xor(dsum, 32, 64);
    if (lane < 16) atomicAdd(&denom_s[lane], dsum);  // lane == r
  }
  __syncthreads();
  if (tid < 16) inv_s[tid] = 1.f / fmaxf(denom_s[tid], 1e-30f);

  // ---- K-loop: wave w, ct = w. 63 x {ds_read A, global B, MFMA}. ----
  f32x4 accP[2] = {{0.f,0.f,0.f,0.f},{0.f,0.f,0.f,0.f}};
  const unsigned short* bb = g_kcWh_pk + (size_t)w * 64 * 512 + lane * 8;
#pragma unroll 4
  for (int kk = 0; kk < 63; ++kk) {
    short8 a = *(const short8*)(P_lds + (size_t)kk * 512 + lane * 8);
    short8 b = *(const short8*)(bb + (size_t)kk * 512);
    accP[kk & 1] =
        __builtin_amdgcn_mfma_f32_16x16x32_bf16(a, b, accP[kk & 1], 0, 0, 0);
  }

  // ---- ex_Eh GEMM: wave w, ct = w ----
  f32x4 accE = {0.f, 0.f, 0.f, 0.f};
#pragma unroll
  for (int kk8 = 0; kk8 < 8; ++kk8) {
    short8 a0 = *(const short8*)(exh_pk_s + kk8 * 512 + lane * 8);
    short8 bf =
        *(const short8*)(g_ET_pk + ((size_t)(w * 8 + kk8)) * 512 + lane * 8);
    accE = __builtin_amdgcn_mfma_f32_16x16x32_bf16(a0, bf, accE, 0, 0, 0);
  }
  __syncthreads();  // K-loop P_lds reads done everywhere; inv_s visible

  // ---- feat = [new_kc | new_kc * ex_Eh] (overlays P_lds) ----
  {
    int col = w * 16 + r;
#pragma unroll
    for (int q = 0; q < 4; ++q) {
      int row = g * 4 + q;
      float nk = (accP[0][q] + accP[1][q]) * inv_s[row];
      feat_s[(size_t)row * FST + col] = f2bf(nk);
      feat_s[(size_t)row * FST + 256 + col] = f2bf(nk * accE[q]);
    }
  }
  __syncthreads();

  // ---- epilogue GEMM: wave w, ct = w; feat(16x512) @ rd_w^T, ELU ----
  f32x4 accO = {0.f, 0.f, 0.f, 0.f};
#pragma unroll
  for (int kt = 0; kt < 16; ++kt) {
    int k = kt * 32 + g * 8;
    short8 a0 = *(const short8*)(feat_s + (size_t)r * FST + k);
    short8 bf =
        *(const short8*)(g_rdw_pk + ((size_t)(w * 16 + kt)) * 512 + lane * 8);
    accO = __builtin_amdgcn_mfma_f32_16x16x32_bf16(a0, bf, accO, 0, 0, 0);
  }
  {
    int col = w * 16 + r;
    float bias = rd_b[col];
#pragma unroll
    for (int q = 0; q < 4; ++q) {
      int row = i0 + g * 4 + q;
      float x = accO[q] + bias;
      out[(size_t)row * 256 + col] = x > 0.f ? x : (__expf(x) - 1.f);
    }
  }
}

extern "C" void kernel_launch(void* const* d_in, const int* in_sizes, int n_in,
                              void* d_out, int out_size, void* d_ws,
                              size_t ws_size, hipStream_t stream) {
  const float* exh  = (const float*)d_in[0];
  const float* kc_h = (const float*)d_in[1];
  const int*   adj  = (const int*)d_in[2];
  const float* W1   = (const float*)d_in[3];
  const float* E    = (const float*)d_in[4];
  const float* a    = (const float*)d_in[5];
  const float* rd_w = (const float*)d_in[6];
  const float* rd_b = (const float*)d_in[7];
  float* out = (float*)d_out;

  prep_kernel<<<66, 256, 0, stream>>>(W1, E, a, rd_w);
  kc_mfma_kernel<<<N_KC / 16, 256, 0, stream>>>(kc_h, a);
  main_kernel<<<N_E / 16, 1024, 0, stream>>>(exh, adj, rd_b, out);
}